// Round 12
// baseline (244.479 us; speedup 1.0000x reference)
//
#include <hip/hip_runtime.h>
#include <math.h>

#define NB 1024
#define NM 50
#define NH 128
#define NI 100000

// flat output offsets (return order)
constexpr size_t OFF_H   = (size_t)NB * NI;              // h_new[None]  (1,B,H)
constexpr size_t OFF_EMB = OFF_H   + (size_t)NB * NH;    // embedded_input (B,1,E)
constexpr size_t OFF_GRU = OFF_EMB + (size_t)NB * NH;    // gru_output (B,1,H)
constexpr size_t OFF_ATT = OFF_GRU + (size_t)NB * NH;    // attn_weights (B,M)

typedef __attribute__((ext_vector_type(8))) short bf16x8;
typedef __attribute__((ext_vector_type(4))) float f32x4;

static __device__ __forceinline__ unsigned short f2bf(float x) {
    unsigned int u = __float_as_uint(x);
    return (unsigned short)((u + 0x7FFFu + ((u >> 16) & 1u)) >> 16);   // RNE
}
static __device__ __forceinline__ float bf2f(unsigned short v) {
    return __uint_as_float((unsigned int)v << 16);
}
static __device__ __forceinline__ float fast_tanh(float x) {
    float cx = fminf(fmaxf(x, -15.0f), 15.0f);
    float e = __expf(2.0f * cx);
    return (e - 1.0f) / (e + 1.0f);
}
static __device__ __forceinline__ float fast_sigmoid(float x) {
    float cx = fminf(fmaxf(x, -30.0f), 30.0f);
    return 1.0f / (1.0f + __expf(-cx));
}
static __device__ __forceinline__ bf16x8 pack8(float4 f0, float4 f1) {
    bf16x8 p;
    p[0] = (short)f2bf(f0.x); p[1] = (short)f2bf(f0.y);
    p[2] = (short)f2bf(f0.z); p[3] = (short)f2bf(f0.w);
    p[4] = (short)f2bf(f1.x); p[5] = (short)f2bf(f1.y);
    p[6] = (short)f2bf(f1.z); p[7] = (short)f2bf(f1.w);
    return p;
}

// ---- Fused kernel: convW slice + attention (MFMA) + GRU, 1 block = 1 batch
// Phase 0 (PRE only): grid-stride f32->bf16 convert of lin_W (overlaps other
//   blocks' attn compute; no barrier needed - pure global streaming).
// Phase 1: attn via MFMA (identical math to previous attn_mfma).
// Phase 2: context kept in LDS; GRU for this batch on t<128 (no cross-block
//   dep: block b produces AND consumes its own context). Fixes old gru
//   kernel's 1-block/CU occupancy and deletes 2 launches + ctx round-trip.
template<bool PRE>
__global__ __launch_bounds__(256) void fused_kernel(
    const float* __restrict__ emb,        // (B,1,E)
    const float* __restrict__ hidden,     // (1,B,H)
    const float* __restrict__ inter,      // (B,M,H)
    const int*   __restrict__ user_list,  // (B,)
    const float* __restrict__ cat_W,      // (U,H,2H)
    const float* __restrict__ cat_b,      // (U,H)
    const float* __restrict__ scale_W,    // (U,1,H)
    const float* __restrict__ w_ih,       // (3H,2E)
    const float* __restrict__ w_hh,       // (3H,H)
    const float* __restrict__ b_ih,       // (3H,)
    const float* __restrict__ b_hh,       // (3H,)
    const float* __restrict__ lin_W,      // (NI,H) f32
    unsigned short* __restrict__ Wbf,     // (NI,H) bf16 out (PRE only)
    float* __restrict__ attn_out,         // (B,M)
    float* __restrict__ out_h,            // (B,H)
    float* __restrict__ out_emb,          // (B,E)
    float* __restrict__ out_gru)          // (B,H)
{
    const int b    = blockIdx.x;
    const int tid  = threadIdx.x;
    const int lane = tid & 63;
    const int wave = tid >> 6;

    __shared__ __align__(16) unsigned short A[64 * 256];  // swizzled [m][k], 32KB
    __shared__ float e_sm[64];
    __shared__ float attn_sm[64];
    __shared__ float x_sm[2 * NH];                        // [emb | ctx] f32

    // ---- phase 0: convert a slice of lin_W (grid-stride across all blocks)
    if (PRE) {
        const int n8 = NI * NH / 8;
        for (int i = b * 256 + tid; i < n8; i += NB * 256) {
            const float* s = lin_W + (size_t)i * 8;
            bf16x8 p = pack8(*(const float4*)s, *(const float4*)(s + 4));
            __builtin_nontemporal_store(p, reinterpret_cast<bf16x8*>(Wbf + (size_t)i * 8));
        }
    }

    const int u = user_list[b];

    // ---- phase 1: attention
    // stage A rows: cols 0-127 = hidden[b], cols 128-255 = inter[b][m] (m<50), else 0
    for (int c = tid; c < 2048; c += 256) {
        int r = c >> 5, s = c & 31;            // row, 8-elem col chunk
        float4 f0, f1;
        if (s < 16) {
            const float* src = hidden + (size_t)b * NH + s * 8;
            f0 = *(const float4*)src; f1 = *(const float4*)(src + 4);
        } else if (r < NM) {
            const float* src = inter + ((size_t)b * NM + r) * NH + (s - 16) * 8;
            f0 = *(const float4*)src; f1 = *(const float4*)(src + 4);
        } else {
            f0 = (float4){0,0,0,0}; f1 = f0;
        }
        int byte = (r * 512 + s * 16) ^ ((r & 7) << 4);
        *reinterpret_cast<bf16x8*>((char*)A + byte) = pack8(f0, f1);
    }
    if (tid < 64) e_sm[tid] = 0.0f;
    __syncthreads();

    const int lrow = lane & 15;
    const int lk8  = (lane >> 4) * 8;          // k sub-offset (elements)

    float bc[2], ws[2];
    #pragma unroll
    for (int nf = 0; nf < 2; ++nf) {
        int h = wave * 32 + nf * 16 + lrow;
        bc[nf] = cat_b[(size_t)u * NH + h];
        ws[nf] = scale_W[(size_t)u * NH + h];
    }

    f32x4 acc[4][2];
    #pragma unroll
    for (int mf = 0; mf < 4; ++mf)
        #pragma unroll
        for (int nf = 0; nf < 2; ++nf)
            acc[mf][nf] = (f32x4){0,0,0,0};

    #pragma unroll
    for (int ks = 0; ks < 8; ++ks) {           // K = 256 = 8 x 32
        bf16x8 bfr[2];
        #pragma unroll
        for (int nf = 0; nf < 2; ++nf) {
            int h = wave * 32 + nf * 16 + lrow;
            const float* wp = cat_W + ((size_t)u * NH + h) * 256 + ks * 32 + lk8;
            bfr[nf] = pack8(*(const float4*)wp, *(const float4*)(wp + 4));
        }
        #pragma unroll
        for (int mf = 0; mf < 4; ++mf) {
            int row  = mf * 16 + lrow;
            int byte = (row * 512 + ks * 64 + lk8 * 2) ^ ((row & 7) << 4);
            bf16x8 a = *reinterpret_cast<const bf16x8*>((char*)A + byte);
            acc[mf][0] = __builtin_amdgcn_mfma_f32_16x16x32_bf16(a, bfr[0], acc[mf][0], 0, 0, 0);
            acc[mf][1] = __builtin_amdgcn_mfma_f32_16x16x32_bf16(a, bfr[1], acc[mf][1], 0, 0, 0);
        }
    }

    // e[m] partial: tanh(acc+bc)*ws summed over this wave's 32 h, then 16-lane reduce
    #pragma unroll
    for (int mf = 0; mf < 4; ++mf) {
        #pragma unroll
        for (int j = 0; j < 4; ++j) {
            float s = fast_tanh(acc[mf][0][j] + bc[0]) * ws[0]
                    + fast_tanh(acc[mf][1][j] + bc[1]) * ws[1];
            s += __shfl_xor(s, 1); s += __shfl_xor(s, 2);
            s += __shfl_xor(s, 4); s += __shfl_xor(s, 8);
            if (lrow == 0) atomicAdd(&e_sm[mf * 16 + (lane >> 4) * 4 + j], s);
        }
    }
    __syncthreads();

    // softmax over m<50 (scale_b is per-batch constant -> softmax-invariant)
    if (tid < 64) {
        float x = (tid < NM) ? e_sm[tid] : -INFINITY;
        float mx = x;
        #pragma unroll
        for (int s = 1; s < 64; s <<= 1) mx = fmaxf(mx, __shfl_xor(mx, s));
        float ex = (tid < NM) ? __expf(x - mx) : 0.0f;
        float sum = ex;
        #pragma unroll
        for (int s = 1; s < 64; s <<= 1) sum += __shfl_xor(sum, s);
        float aw = ex / sum;
        attn_sm[tid] = aw;
        if (tid < NM) attn_out[(size_t)b * NM + tid] = aw;
    }
    __syncthreads();

    // context[h] -> LDS x_sm[NH+h]; emb -> x_sm[h]
    if (tid < NH) {
        float c = 0.0f;
        #pragma unroll
        for (int m = 0; m < NM; ++m) {
            int byte = (m * 512 + (NH + tid) * 2) ^ ((m & 7) << 4);
            c = fmaf(attn_sm[m], bf2f(*reinterpret_cast<const unsigned short*>((char*)A + byte)), c);
        }
        x_sm[NH + tid] = c;
        x_sm[tid]      = emb[(size_t)b * NH + tid];
    }
    __syncthreads();

    // ---- phase 2: GRU for batch b (t < 128)
    if (tid < NH) {
        const int t = tid;
        const float* wr = w_ih + (size_t)t * 256;
        const float* wz = w_ih + (size_t)(NH + t) * 256;
        const float* wn = w_ih + (size_t)(2 * NH + t) * 256;
        float gr = b_ih[t], gz = b_ih[NH + t], gn = b_ih[2 * NH + t];
        for (int i4 = 0; i4 < 64; ++i4) {
            float4 wr4 = *(const float4*)(wr + i4 * 4);
            float4 wz4 = *(const float4*)(wz + i4 * 4);
            float4 wn4 = *(const float4*)(wn + i4 * 4);
            float4 x4  = *(const float4*)(&x_sm[i4 * 4]);
            gr += wr4.x * x4.x + wr4.y * x4.y + wr4.z * x4.z + wr4.w * x4.w;
            gz += wz4.x * x4.x + wz4.y * x4.y + wz4.z * x4.z + wz4.w * x4.w;
            gn += wn4.x * x4.x + wn4.y * x4.y + wn4.z * x4.z + wn4.w * x4.w;
        }
        const float* vr = w_hh + (size_t)t * NH;
        const float* vz = w_hh + (size_t)(NH + t) * NH;
        const float* vn = w_hh + (size_t)(2 * NH + t) * NH;
        float hr = b_hh[t], hz = b_hh[NH + t], hn = b_hh[2 * NH + t];
        const float* hvec = hidden + (size_t)b * NH;
        for (int i4 = 0; i4 < 32; ++i4) {
            float4 vr4 = *(const float4*)(vr + i4 * 4);
            float4 vz4 = *(const float4*)(vz + i4 * 4);
            float4 vn4 = *(const float4*)(vn + i4 * 4);
            float4 h4  = *(const float4*)(hvec + i4 * 4);
            hr += vr4.x * h4.x + vr4.y * h4.y + vr4.z * h4.z + vr4.w * h4.w;
            hz += vz4.x * h4.x + vz4.y * h4.y + vz4.z * h4.z + vz4.w * h4.w;
            hn += vn4.x * h4.x + vn4.y * h4.y + vn4.z * h4.z + vn4.w * h4.w;
        }
        float r = fast_sigmoid(gr + hr);
        float z = fast_sigmoid(gz + hz);
        float n = fast_tanh(gn + r * hn);
        float h0 = hvec[t];
        float hnew = (1.0f - z) * n + z * h0;
        size_t o = (size_t)b * NH + t;
        out_h[o]   = hnew;
        out_gru[o] = hnew;
        out_emb[o] = x_sm[t];
    }
}

// ---------------- Kernel 3: output projection, bf16 MFMA (low-VGPR) ------
template<bool PRE>
__global__ __launch_bounds__(256, 4) void out_mfma(
    const float* __restrict__ hnew,           // (B,H)
    const float* __restrict__ lin_W,          // (NI,H) f32
    const unsigned short* __restrict__ Wbf,   // (NI,H) bf16 (PRE only)
    const float* __restrict__ lin_b,          // (NI,)
    float* __restrict__ out)                  // (B,NI)
{
    const int L  = blockIdx.x;                 // 0..6255 ; 6256 = 8 XCDs * 782
    const int wg = (L & 7) * 782 + (L >> 3);   // bijective chunk-per-XCD remap
    const int mb = wg & 15;
    const int nb = wg >> 4;

    const int tid  = threadIdx.x;
    const int lane = tid & 63;
    const int wave = tid >> 6;

    const int b0 = mb * 64;
    const int n0 = nb * 256 + wave * 64;

    __shared__ __align__(16) unsigned char smem[32 * 260 * 4];   // 33.3KB union
    unsigned short* As = (unsigned short*)smem;                  // [64][128] bf16 swizzled (16KB)
    float (*Cs)[260]   = (float(*)[260])smem;                    // [32][260] f32

    // stage A = hnew tile, f32 -> bf16, XOR-swizzled
    for (int c = tid; c < 1024; c += 256) {
        int r = c >> 4;
        int s = c & 15;
        const float* src = hnew + (size_t)(b0 + r) * NH + s * 8;
        bf16x8 p = pack8(*(const float4*)src, *(const float4*)(src + 4));
        int byte = (r * 256 + s * 16) ^ ((r & 7) << 4);
        *reinterpret_cast<bf16x8*>((char*)As + byte) = p;
    }
    __syncthreads();

    const int lrow = lane & 15;
    const int g    = lane >> 4;
    const int lk8  = g * 8;

    f32x4 acc[4][4];   // [mf][nf] = 64 VGPR
    #pragma unroll
    for (int mf = 0; mf < 4; ++mf)
        #pragma unroll
        for (int nf = 0; nf < 4; ++nf)
            acc[mf][nf] = (f32x4){0,0,0,0};

    #pragma unroll
    for (int ks = 0; ks < 4; ++ks) {
        bf16x8 av[4];
        #pragma unroll
        for (int mf = 0; mf < 4; ++mf) {
            int row  = mf * 16 + lrow;
            int byte = (row * 256 + ks * 64 + lk8 * 2) ^ ((row & 7) << 4);
            av[mf] = *reinterpret_cast<const bf16x8*>((char*)As + byte);
        }
        bf16x8 bv[4];
        #pragma unroll
        for (int nf = 0; nf < 4; ++nf) {
            int n = n0 + nf * 16 + lrow;
            const size_t nrow = (size_t)(n < NI ? n : 0) * NH;
            if (PRE) {
                bv[nf] = *reinterpret_cast<const bf16x8*>(Wbf + nrow + ks * 32 + lk8);
            } else {
                const float* wr = lin_W + nrow + ks * 32 + lk8;
                bv[nf] = pack8(*(const float4*)wr, *(const float4*)(wr + 4));
            }
        }
        // swapped operands: A-op = W rows (n as M-dim), B-op = hnew (m as N-dim)
        #pragma unroll
        for (int nf = 0; nf < 4; ++nf)
            #pragma unroll
            for (int mf = 0; mf < 4; ++mf)
                acc[mf][nf] = __builtin_amdgcn_mfma_f32_16x16x32_bf16(
                    bv[nf], av[mf], acc[mf][nf], 0, 0, 0);
    }

    // bias (loaded after K-loop to keep K-loop VGPR low)
    f32x4 bias4[4];
    #pragma unroll
    for (int nf = 0; nf < 4; ++nf) {
        int nq = n0 + nf * 16 + g * 4;
        if (nq > NI - 4) nq = NI - 4;           // clamp (stores are guarded)
        const float4 bv = *(const float4*)(&lin_b[nq]);
        bias4[nf] = (f32x4){bv.x, bv.y, bv.z, bv.w};
    }

    // two-pass epilogue: 32 rows per half
    #pragma unroll
    for (int half = 0; half < 2; ++half) {
        __syncthreads();
        #pragma unroll
        for (int mf2 = 0; mf2 < 2; ++mf2) {
            int mf = half * 2 + mf2;
            int rloc = mf2 * 16 + lrow;
            #pragma unroll
            for (int nf = 0; nf < 4; ++nf) {
                int colq = wave * 64 + nf * 16 + g * 4;
                *(f32x4*)(&Cs[rloc][colq]) = acc[mf][nf] + bias4[nf];
            }
        }
        __syncthreads();
        #pragma unroll
        for (int p = 0; p < 8; ++p) {
            int rloc = p * 4 + wave;
            int col4 = lane * 4;
            int n    = nb * 256 + col4;
            if (n < NI) {
                f32x4 v = *(const f32x4*)(&Cs[rloc][col4]);
                __builtin_nontemporal_store(v,
                    (f32x4*)(&out[(size_t)(b0 + half * 32 + rloc) * NI + n]));
            }
        }
    }
}

extern "C" void kernel_launch(void* const* d_in, const int* in_sizes, int n_in,
                              void* d_out, int out_size, void* d_ws, size_t ws_size,
                              hipStream_t stream) {
    const float* emb      = (const float*)d_in[0];
    const float* hidden   = (const float*)d_in[1];
    const float* inter    = (const float*)d_in[2];
    // d_in[3] = delta_t_h : unused by the reference
    const int*   user     = (const int*)  d_in[4];
    const float* w_ih     = (const float*)d_in[5];
    const float* w_hh     = (const float*)d_in[6];
    const float* b_ih     = (const float*)d_in[7];
    const float* b_hh     = (const float*)d_in[8];
    const float* lin_W    = (const float*)d_in[9];
    const float* lin_b    = (const float*)d_in[10];
    const float* cat_W    = (const float*)d_in[11];
    const float* cat_b    = (const float*)d_in[12];
    const float* scale_W  = (const float*)d_in[13];
    // d_in[14] = scale_b : per-batch constant energy shift -> softmax invariant

    float* out = (float*)d_out;
    unsigned short* Wbf = (unsigned short*)d_ws;
    const size_t need = (size_t)NI * NH * 2;                 // 25.6 MB
    const bool pre = (ws_size >= need);

    if (pre) {
        fused_kernel<true><<<NB, 256, 0, stream>>>(
            emb, hidden, inter, user, cat_W, cat_b, scale_W,
            w_ih, w_hh, b_ih, b_hh, lin_W, Wbf,
            out + OFF_ATT, out + OFF_H, out + OFF_EMB, out + OFF_GRU);
        out_mfma<true><<<6256, 256, 0, stream>>>(out + OFF_H, lin_W, Wbf, lin_b, out);
    } else {
        fused_kernel<false><<<NB, 256, 0, stream>>>(
            emb, hidden, inter, user, cat_W, cat_b, scale_W,
            w_ih, w_hh, b_ih, b_hh, lin_W, nullptr,
            out + OFF_ATT, out + OFF_H, out + OFF_EMB, out + OFF_GRU);
        out_mfma<false><<<6256, 256, 0, stream>>>(out + OFF_H, lin_W, nullptr, lin_b, out);
    }
}

// Round 13
// 196.083 us; speedup vs baseline: 1.2468x; 1.2468x over previous
//
#include <hip/hip_runtime.h>
#include <math.h>

#define NB 1024
#define NM 50
#define NH 128
#define NI 100000

// flat output offsets (return order)
constexpr size_t OFF_H   = (size_t)NB * NI;              // h_new[None]  (1,B,H)
constexpr size_t OFF_EMB = OFF_H   + (size_t)NB * NH;    // embedded_input (B,1,E)
constexpr size_t OFF_GRU = OFF_EMB + (size_t)NB * NH;    // gru_output (B,1,H)
constexpr size_t OFF_ATT = OFF_GRU + (size_t)NB * NH;    // attn_weights (B,M)

typedef __attribute__((ext_vector_type(8))) short bf16x8;
typedef __attribute__((ext_vector_type(4))) float f32x4;

static __device__ __forceinline__ unsigned short f2bf(float x) {
    unsigned int u = __float_as_uint(x);
    return (unsigned short)((u + 0x7FFFu + ((u >> 16) & 1u)) >> 16);   // RNE
}
static __device__ __forceinline__ float bf2f(unsigned short v) {
    return __uint_as_float((unsigned int)v << 16);
}
static __device__ __forceinline__ float fast_tanh(float x) {
    float cx = fminf(fmaxf(x, -15.0f), 15.0f);
    float e = __expf(2.0f * cx);
    return (e - 1.0f) / (e + 1.0f);
}
static __device__ __forceinline__ float fast_sigmoid(float x) {
    float cx = fminf(fmaxf(x, -30.0f), 30.0f);
    return 1.0f / (1.0f + __expf(-cx));
}
static __device__ __forceinline__ bf16x8 pack8(float4 f0, float4 f1) {
    bf16x8 p;
    p[0] = (short)f2bf(f0.x); p[1] = (short)f2bf(f0.y);
    p[2] = (short)f2bf(f0.z); p[3] = (short)f2bf(f0.w);
    p[4] = (short)f2bf(f1.x); p[5] = (short)f2bf(f1.y);
    p[6] = (short)f2bf(f1.z); p[7] = (short)f2bf(f1.w);
    return p;
}

// ---- Kernel A: convW slice + attention (MFMA), 1 block = 1 batch --------
// conv streaming (77MB) hides under 1024 blocks' attn MFMA; GRU NOT fused
// (R12 showed per-block GRU weight re-reads cost +37us).
template<bool PRE>
__global__ __launch_bounds__(256) void attn_conv(
    const float* __restrict__ hidden,     // (1,B,H)
    const float* __restrict__ inter,      // (B,M,H)
    const int*   __restrict__ user_list,  // (B,)
    const float* __restrict__ cat_W,      // (U,H,2H)
    const float* __restrict__ cat_b,      // (U,H)
    const float* __restrict__ scale_W,    // (U,1,H)
    const float* __restrict__ lin_W,      // (NI,H) f32
    unsigned short* __restrict__ Wbf,     // (NI,H) bf16 out (PRE only)
    float* __restrict__ attn_out,         // (B,M)
    float* __restrict__ context)          // (B,H) scratch
{
    const int b    = blockIdx.x;
    const int tid  = threadIdx.x;
    const int lane = tid & 63;
    const int wave = tid >> 6;

    __shared__ __align__(16) unsigned short A[64 * 256];  // swizzled [m][k], 32KB
    __shared__ float e_sm[64];
    __shared__ float attn_sm[64];

    // phase 0: convert a slice of lin_W (grid-stride; overlaps attn of other blocks)
    if (PRE) {
        const int n8 = NI * NH / 8;
        for (int i = b * 256 + tid; i < n8; i += NB * 256) {
            const float* s = lin_W + (size_t)i * 8;
            bf16x8 p = pack8(*(const float4*)s, *(const float4*)(s + 4));
            __builtin_nontemporal_store(p, reinterpret_cast<bf16x8*>(Wbf + (size_t)i * 8));
        }
    }

    const int u = user_list[b];

    // stage A rows: cols 0-127 = hidden[b], cols 128-255 = inter[b][m] (m<50), else 0
    for (int c = tid; c < 2048; c += 256) {
        int r = c >> 5, s = c & 31;
        float4 f0, f1;
        if (s < 16) {
            const float* src = hidden + (size_t)b * NH + s * 8;
            f0 = *(const float4*)src; f1 = *(const float4*)(src + 4);
        } else if (r < NM) {
            const float* src = inter + ((size_t)b * NM + r) * NH + (s - 16) * 8;
            f0 = *(const float4*)src; f1 = *(const float4*)(src + 4);
        } else {
            f0 = (float4){0,0,0,0}; f1 = f0;
        }
        int byte = (r * 512 + s * 16) ^ ((r & 7) << 4);
        *reinterpret_cast<bf16x8*>((char*)A + byte) = pack8(f0, f1);
    }
    if (tid < 64) e_sm[tid] = 0.0f;
    __syncthreads();

    const int lrow = lane & 15;
    const int lk8  = (lane >> 4) * 8;

    float bc[2], ws[2];
    #pragma unroll
    for (int nf = 0; nf < 2; ++nf) {
        int h = wave * 32 + nf * 16 + lrow;
        bc[nf] = cat_b[(size_t)u * NH + h];
        ws[nf] = scale_W[(size_t)u * NH + h];
    }

    f32x4 acc[4][2];
    #pragma unroll
    for (int mf = 0; mf < 4; ++mf)
        #pragma unroll
        for (int nf = 0; nf < 2; ++nf)
            acc[mf][nf] = (f32x4){0,0,0,0};

    #pragma unroll
    for (int ks = 0; ks < 8; ++ks) {           // K = 256 = 8 x 32
        bf16x8 bfr[2];
        #pragma unroll
        for (int nf = 0; nf < 2; ++nf) {
            int h = wave * 32 + nf * 16 + lrow;
            const float* wp = cat_W + ((size_t)u * NH + h) * 256 + ks * 32 + lk8;
            bfr[nf] = pack8(*(const float4*)wp, *(const float4*)(wp + 4));
        }
        #pragma unroll
        for (int mf = 0; mf < 4; ++mf) {
            int row  = mf * 16 + lrow;
            int byte = (row * 512 + ks * 64 + lk8 * 2) ^ ((row & 7) << 4);
            bf16x8 a = *reinterpret_cast<const bf16x8*>((char*)A + byte);
            acc[mf][0] = __builtin_amdgcn_mfma_f32_16x16x32_bf16(a, bfr[0], acc[mf][0], 0, 0, 0);
            acc[mf][1] = __builtin_amdgcn_mfma_f32_16x16x32_bf16(a, bfr[1], acc[mf][1], 0, 0, 0);
        }
    }

    #pragma unroll
    for (int mf = 0; mf < 4; ++mf) {
        #pragma unroll
        for (int j = 0; j < 4; ++j) {
            float s = fast_tanh(acc[mf][0][j] + bc[0]) * ws[0]
                    + fast_tanh(acc[mf][1][j] + bc[1]) * ws[1];
            s += __shfl_xor(s, 1); s += __shfl_xor(s, 2);
            s += __shfl_xor(s, 4); s += __shfl_xor(s, 8);
            if (lrow == 0) atomicAdd(&e_sm[mf * 16 + (lane >> 4) * 4 + j], s);
        }
    }
    __syncthreads();

    if (tid < 64) {
        float x = (tid < NM) ? e_sm[tid] : -INFINITY;
        float mx = x;
        #pragma unroll
        for (int s = 1; s < 64; s <<= 1) mx = fmaxf(mx, __shfl_xor(mx, s));
        float ex = (tid < NM) ? __expf(x - mx) : 0.0f;
        float sum = ex;
        #pragma unroll
        for (int s = 1; s < 64; s <<= 1) sum += __shfl_xor(sum, s);
        float aw = ex / sum;
        attn_sm[tid] = aw;
        if (tid < NM) attn_out[(size_t)b * NM + tid] = aw;
    }
    __syncthreads();

    if (tid < NH) {
        float c = 0.0f;
        #pragma unroll
        for (int m = 0; m < NM; ++m) {
            int byte = (m * 512 + (NH + tid) * 2) ^ ((m & 7) << 4);
            c = fmaf(attn_sm[m], bf2f(*reinterpret_cast<const unsigned short*>((char*)A + byte)), c);
        }
        context[(size_t)b * NH + tid] = c;
    }
}

// ---- Kernel B: GRU via MFMA, 1 block = 16 batches, 64 blocks -------------
// gi = [emb|ctx](16x256) @ w_ih^T(384x256), gh = h(16x128) @ w_hh^T(384x128)
// using the verified swapped-operand pattern (D col = batch, row = n).
// Gates combined through LDS G[384][17] (pad 17: h-stride 16 would be a
// 2-bank 32-way conflict). Coalesced weight reads as B-fragments.
__global__ __launch_bounds__(256) void gru_mfma(
    const float* __restrict__ emb,        // (B,1,E)
    const float* __restrict__ hidden,     // (1,B,H)
    const float* __restrict__ context,    // (B,H)
    const float* __restrict__ w_ih,       // (3H,2E)
    const float* __restrict__ w_hh,       // (3H,H)
    const float* __restrict__ b_ih,       // (3H,)
    const float* __restrict__ b_hh,       // (3H,)
    float* __restrict__ out_h,            // (B,H)
    float* __restrict__ out_emb,          // (B,E)
    float* __restrict__ out_gru)          // (B,H)
{
    const int b0   = blockIdx.x * 16;
    const int tid  = threadIdx.x;
    const int lane = tid & 63;
    const int wave = tid >> 6;

    __shared__ __align__(16) unsigned short Xs[16 * 256];  // [b][k] bf16 swizzled, 8KB
    __shared__ __align__(16) unsigned short Hs[16 * 128];  // [b][k] bf16 swizzled, 4KB
    __shared__ float Gi[384][17];                          // 25.5KB
    __shared__ float Gh[384][17];                          // 25.5KB

    // stage x = [emb|ctx] and h, f32 -> bf16, XOR-swizzled rows
    for (int c = tid; c < 768; c += 256) {
        if (c < 512) {
            int r = c >> 5, s = c & 31;        // x row, 8-col chunk
            const float* src = (s < 16)
                ? emb     + (size_t)(b0 + r) * NH + s * 8
                : context + (size_t)(b0 + r) * NH + (s - 16) * 8;
            int byte = (r * 512 + s * 16) ^ ((r & 7) << 4);
            *reinterpret_cast<bf16x8*>((char*)Xs + byte) =
                pack8(*(const float4*)src, *(const float4*)(src + 4));
        } else {
            int cc = c - 512;
            int r = cc >> 4, s = cc & 15;      // h row, 8-col chunk
            const float* src = hidden + (size_t)(b0 + r) * NH + s * 8;
            int byte = (r * 256 + s * 16) ^ ((r & 7) << 4);
            *reinterpret_cast<bf16x8*>((char*)Hs + byte) =
                pack8(*(const float4*)src, *(const float4*)(src + 4));
        }
    }
    __syncthreads();

    const int lrow = lane & 15;
    const int g    = lane >> 4;
    const int lk8  = g * 8;

    // A-operand fragments from x / h (batch = lrow)
    bf16x8 xa[8], ha[4];
    #pragma unroll
    for (int ks = 0; ks < 8; ++ks) {
        int byte = (lrow * 512 + ks * 64 + lk8 * 2) ^ ((lrow & 7) << 4);
        xa[ks] = *reinterpret_cast<const bf16x8*>((char*)Xs + byte);
    }
    #pragma unroll
    for (int ks = 0; ks < 4; ++ks) {
        int byte = (lrow * 256 + ks * 64 + lk8 * 2) ^ ((lrow & 7) << 4);
        ha[ks] = *reinterpret_cast<const bf16x8*>((char*)Hs + byte);
    }

    // wave w owns n in [w*96, w*96+96): 6 fragments
    #pragma unroll
    for (int nf = 0; nf < 6; ++nf) {
        const int n = wave * 96 + nf * 16 + lrow;     // weight row (n < 384)
        f32x4 ai = (f32x4){0,0,0,0};
        f32x4 ah = (f32x4){0,0,0,0};
        const float* wi = w_ih + (size_t)n * 256;
        #pragma unroll
        for (int ks = 0; ks < 8; ++ks) {
            const float* wp = wi + ks * 32 + lk8;
            bf16x8 bv = pack8(*(const float4*)wp, *(const float4*)(wp + 4));
            ai = __builtin_amdgcn_mfma_f32_16x16x32_bf16(bv, xa[ks], ai, 0, 0, 0);
        }
        const float* wh = w_hh + (size_t)n * NH;
        #pragma unroll
        for (int ks = 0; ks < 4; ++ks) {
            const float* wp = wh + ks * 32 + lk8;
            bf16x8 bv = pack8(*(const float4*)wp, *(const float4*)(wp + 4));
            ah = __builtin_amdgcn_mfma_f32_16x16x32_bf16(bv, ha[ks], ah, 0, 0, 0);
        }
        // D: col = batch = lane&15, row = g*4+j within fragment
        #pragma unroll
        for (int j = 0; j < 4; ++j) {
            int nrow = wave * 96 + nf * 16 + g * 4 + j;
            Gi[nrow][lrow] = ai[j];
            Gh[nrow][lrow] = ah[j];
        }
    }
    __syncthreads();

    // combine gates: 2048 outputs, 8 per thread
    #pragma unroll
    for (int k = 0; k < 8; ++k) {
        int idx = k * 256 + tid;
        int bb  = idx >> 7;          // 0..15
        int h   = idx & 127;
        float gr = Gi[h][bb]        + b_ih[h];
        float gz = Gi[128 + h][bb]  + b_ih[128 + h];
        float gn = Gi[256 + h][bb]  + b_ih[256 + h];
        float hr = Gh[h][bb]        + b_hh[h];
        float hz = Gh[128 + h][bb]  + b_hh[128 + h];
        float hn = Gh[256 + h][bb]  + b_hh[256 + h];
        float r = fast_sigmoid(gr + hr);
        float z = fast_sigmoid(gz + hz);
        float n = fast_tanh(gn + r * hn);
        size_t o = (size_t)(b0 + bb) * NH + h;
        float h0 = hidden[o];
        float hnew = (1.0f - z) * n + z * h0;
        out_h[o]   = hnew;
        out_gru[o] = hnew;
        out_emb[o] = emb[o];         // exact f32 copy
    }
}

// ---- Kernel C: output projection, bf16 MFMA (low-VGPR, R11) --------------
template<bool PRE>
__global__ __launch_bounds__(256, 4) void out_mfma(
    const float* __restrict__ hnew,           // (B,H)
    const float* __restrict__ lin_W,          // (NI,H) f32
    const unsigned short* __restrict__ Wbf,   // (NI,H) bf16 (PRE only)
    const float* __restrict__ lin_b,          // (NI,)
    float* __restrict__ out)                  // (B,NI)
{
    const int L  = blockIdx.x;                 // 0..6255 ; 6256 = 8 XCDs * 782
    const int wg = (L & 7) * 782 + (L >> 3);   // bijective chunk-per-XCD remap
    const int mb = wg & 15;
    const int nb = wg >> 4;

    const int tid  = threadIdx.x;
    const int lane = tid & 63;
    const int wave = tid >> 6;

    const int b0 = mb * 64;
    const int n0 = nb * 256 + wave * 64;

    __shared__ __align__(16) unsigned char smem[32 * 260 * 4];   // 33.3KB union
    unsigned short* As = (unsigned short*)smem;                  // [64][128] bf16 swizzled
    float (*Cs)[260]   = (float(*)[260])smem;                    // [32][260] f32

    for (int c = tid; c < 1024; c += 256) {
        int r = c >> 4;
        int s = c & 15;
        const float* src = hnew + (size_t)(b0 + r) * NH + s * 8;
        bf16x8 p = pack8(*(const float4*)src, *(const float4*)(src + 4));
        int byte = (r * 256 + s * 16) ^ ((r & 7) << 4);
        *reinterpret_cast<bf16x8*>((char*)As + byte) = p;
    }
    __syncthreads();

    const int lrow = lane & 15;
    const int g    = lane >> 4;
    const int lk8  = g * 8;

    f32x4 acc[4][4];
    #pragma unroll
    for (int mf = 0; mf < 4; ++mf)
        #pragma unroll
        for (int nf = 0; nf < 4; ++nf)
            acc[mf][nf] = (f32x4){0,0,0,0};

    #pragma unroll
    for (int ks = 0; ks < 4; ++ks) {
        bf16x8 av[4];
        #pragma unroll
        for (int mf = 0; mf < 4; ++mf) {
            int row  = mf * 16 + lrow;
            int byte = (row * 256 + ks * 64 + lk8 * 2) ^ ((row & 7) << 4);
            av[mf] = *reinterpret_cast<const bf16x8*>((char*)As + byte);
        }
        bf16x8 bv[4];
        #pragma unroll
        for (int nf = 0; nf < 4; ++nf) {
            int n = n0 + nf * 16 + lrow;
            const size_t nrow = (size_t)(n < NI ? n : 0) * NH;
            if (PRE) {
                bv[nf] = *reinterpret_cast<const bf16x8*>(Wbf + nrow + ks * 32 + lk8);
            } else {
                const float* wr = lin_W + nrow + ks * 32 + lk8;
                bv[nf] = pack8(*(const float4*)wr, *(const float4*)(wr + 4));
            }
        }
        #pragma unroll
        for (int nf = 0; nf < 4; ++nf)
            #pragma unroll
            for (int mf = 0; mf < 4; ++mf)
                acc[mf][nf] = __builtin_amdgcn_mfma_f32_16x16x32_bf16(
                    bv[nf], av[mf], acc[mf][nf], 0, 0, 0);
    }

    f32x4 bias4[4];
    #pragma unroll
    for (int nf = 0; nf < 4; ++nf) {
        int nq = n0 + nf * 16 + g * 4;
        if (nq > NI - 4) nq = NI - 4;
        const float4 bv = *(const float4*)(&lin_b[nq]);
        bias4[nf] = (f32x4){bv.x, bv.y, bv.z, bv.w};
    }

    #pragma unroll
    for (int half = 0; half < 2; ++half) {
        __syncthreads();
        #pragma unroll
        for (int mf2 = 0; mf2 < 2; ++mf2) {
            int mf = half * 2 + mf2;
            int rloc = mf2 * 16 + lrow;
            #pragma unroll
            for (int nf = 0; nf < 4; ++nf) {
                int colq = wave * 64 + nf * 16 + g * 4;
                *(f32x4*)(&Cs[rloc][colq]) = acc[mf][nf] + bias4[nf];
            }
        }
        __syncthreads();
        #pragma unroll
        for (int p = 0; p < 8; ++p) {
            int rloc = p * 4 + wave;
            int col4 = lane * 4;
            int n    = nb * 256 + col4;
            if (n < NI) {
                f32x4 v = *(const f32x4*)(&Cs[rloc][col4]);
                __builtin_nontemporal_store(v,
                    (f32x4*)(&out[(size_t)(b0 + half * 32 + rloc) * NI + n]));
            }
        }
    }
}

extern "C" void kernel_launch(void* const* d_in, const int* in_sizes, int n_in,
                              void* d_out, int out_size, void* d_ws, size_t ws_size,
                              hipStream_t stream) {
    const float* emb      = (const float*)d_in[0];
    const float* hidden   = (const float*)d_in[1];
    const float* inter    = (const float*)d_in[2];
    // d_in[3] = delta_t_h : unused by the reference
    const int*   user     = (const int*)  d_in[4];
    const float* w_ih     = (const float*)d_in[5];
    const float* w_hh     = (const float*)d_in[6];
    const float* b_ih     = (const float*)d_in[7];
    const float* b_hh     = (const float*)d_in[8];
    const float* lin_W    = (const float*)d_in[9];
    const float* lin_b    = (const float*)d_in[10];
    const float* cat_W    = (const float*)d_in[11];
    const float* cat_b    = (const float*)d_in[12];
    const float* scale_W  = (const float*)d_in[13];
    // d_in[14] = scale_b : per-batch constant energy shift -> softmax invariant

    float* out = (float*)d_out;
    const size_t wbf_bytes = (size_t)NI * NH * 2;            // 25.6 MB
    const size_t need = wbf_bytes + 512 * 1024;
    const bool pre = (ws_size >= need);

    unsigned short* Wbf = (unsigned short*)d_ws;
    float* ctx = pre ? (float*)((char*)d_ws + wbf_bytes) : (float*)d_ws;

    if (pre) {
        attn_conv<true><<<NB, 256, 0, stream>>>(hidden, inter, user, cat_W, cat_b,
                                                scale_W, lin_W, Wbf, out + OFF_ATT, ctx);
        gru_mfma<<<NB / 16, 256, 0, stream>>>(emb, hidden, ctx, w_ih, w_hh, b_ih, b_hh,
                                              out + OFF_H, out + OFF_EMB, out + OFF_GRU);
        out_mfma<true><<<6256, 256, 0, stream>>>(out + OFF_H, lin_W, Wbf, lin_b, out);
    } else {
        attn_conv<false><<<NB, 256, 0, stream>>>(hidden, inter, user, cat_W, cat_b,
                                                 scale_W, lin_W, nullptr, out + OFF_ATT, ctx);
        gru_mfma<<<NB / 16, 256, 0, stream>>>(emb, hidden, ctx, w_ih, w_hh, b_ih, b_hh,
                                              out + OFF_H, out + OFF_EMB, out + OFF_GRU);
        out_mfma<false><<<6256, 256, 0, stream>>>(out + OFF_H, lin_W, nullptr, lin_b, out);
    }
}